// Round 1
// baseline (478.893 us; speedup 1.0000x reference)
//
#include <hip/hip_runtime.h>
#include <hip/hip_bf16.h>

#define D_EMB 128
#define T_HIST 200
#define T_PAD 208
#define NG 6400      // float4 granules per batch row: 200*128/4
#define NG_PAD 6656  // 208*32
#define ITERS 64
#define NBLK 256

typedef float f32x4 __attribute__((ext_vector_type(4)));
typedef short bf16x8 __attribute__((ext_vector_type(8)));

// manual RNE f32->bf16 (inputs are finite; no NaN path keeps it ~4 VALU ops)
__device__ __forceinline__ short f2bf(float f) {
    unsigned u = __builtin_bit_cast(unsigned, f);
    u += 0x7fffu + ((u >> 16) & 1u);
    return (short)(u >> 16);
}

// Pack W [d][e] f32 into MFMA B-fragment order, bf16.
// frag id = ks*8 + nt (ks: k-step of 32, nt: 16-wide n tile).
// lane layout: n = nt*16 + (lane&15); k = ks*32 + (lane>>4)*8 + j, j=0..7.
__global__ void pack_w_kernel(const float* __restrict__ W, short* __restrict__ wfrag) {
    int tid = blockIdx.x * blockDim.x + threadIdx.x;  // 0..2047
    int fragid = tid >> 6;
    int lane = tid & 63;
    int ks = fragid >> 3;
    int nt = fragid & 7;
    int n = nt * 16 + (lane & 15);
    int k0 = ks * 32 + (lane >> 4) * 8;
    bf16x8 r;
#pragma unroll
    for (int j = 0; j < 8; ++j) r[j] = f2bf(W[(k0 + j) * D_EMB + n]);
    ((bf16x8*)wfrag)[fragid * 64 + lane] = r;
}

// TW[b][e] = bias[e] + sum_d target[b][d] * W[d][e]   (full f32)
__global__ void tw_kernel(const float* __restrict__ target, const float* __restrict__ W,
                          const float* __restrict__ bias, float* __restrict__ TW) {
    int e = threadIdx.x;      // 0..127
    int b0 = blockIdx.x * 8;  // 8 rows per block amortizes W row reads
    float bv = bias[e];
    float acc[8];
#pragma unroll
    for (int i = 0; i < 8; ++i) acc[i] = bv;
    for (int d = 0; d < D_EMB; ++d) {
        float wv = W[d * D_EMB + e];
#pragma unroll
        for (int i = 0; i < 8; ++i)
            acc[i] = fmaf(target[(size_t)(b0 + i) * D_EMB + d], wv, acc[i]);
    }
#pragma unroll
    for (int i = 0; i < 8; ++i) TW[(size_t)(b0 + i) * D_EMB + e] = acc[i];
}

// Persistent fused kernel: 256 blocks (1/CU) x 512 threads (8 waves), 64 b's each.
// LDS hist tile is f32, XOR-swizzled at 16B-granule level: logical (t,c) lives at
// physical granule t*32 + (c ^ (t&7)). Swizzle applied on the GLOBAL gather side
// (per-lane source index) so stage writes are linear & conflict-free.
__launch_bounds__(512, 2)
__global__ void attn_main(const float* __restrict__ hist,
                          const float* __restrict__ TW,
                          const float* __restrict__ q,
                          const short* __restrict__ wfrag,
                          float* __restrict__ out) {
    __shared__ f32x4 h4[NG_PAD];             // 106496 B
    __shared__ float s_tw[D_EMB];            // 512 B
    __shared__ float s_logits[2][T_PAD];     // 1664 B (two pair-half partials)
    __shared__ float s_scores[T_PAD];        // 832 B (unnormalized exp)
    __shared__ float s_red[16];              // 64 B
    __shared__ float s_p2[16][D_EMB];        // 8192 B

    const int tid = threadIdx.x;
    const int l = tid & 63;
    const int w = tid >> 6;
    const int p = w & 3;    // pair id: m-tiles {p, p+4, p+8, p+12<13}
    const int hf = w >> 2;  // half: owns n-tiles hf*4 .. hf*4+3
    const int l15 = l & 15;
    const int lg = l >> 4;
    const f32x4 vzero = {0.f, 0.f, 0.f, 0.f};

    // resident B fragments: 4 ks x 4 local-nt = 64 VGPR, loaded once (L2-hot)
    bf16x8 Bf[4][4];
#pragma unroll
    for (int ks = 0; ks < 4; ++ks)
#pragma unroll
        for (int j = 0; j < 4; ++j)
            Bf[ks][j] = ((const bf16x8*)wfrag)[(ks * 8 + hf * 4 + j) * 64 + l];

    float qv[4];
#pragma unroll
    for (int j = 0; j < 4; ++j) qv[j] = q[hf * 64 + j * 16 + l15];

    // zero the 8 pad rows (t=200..207) once; never overwritten
    if (tid < 256) h4[NG + tid] = vzero;

    // per-thread global gather indices (constant across iterations):
    // physical granule s = tid + k*512 holds logical (t = s>>5, c = (s&31)^(t&7))
    int gidx[13];
#pragma unroll
    for (int k = 0; k < 13; ++k) {
        int s = tid + k * 512;
        int t = s >> 5;
        gidx[k] = t * 32 + ((s & 31) ^ (t & 7));
    }

    int b = blockIdx.x * ITERS;
    const f32x4* gh = (const f32x4*)hist + (size_t)b * NG;
    f32x4 stg[13];
#pragma unroll
    for (int k = 0; k < 12; ++k) stg[k] = gh[gidx[k]];
    if (tid < 256) stg[12] = gh[gidx[12]];
    float twstg = (tid < 128) ? TW[(size_t)b * D_EMB + tid] : 0.f;

    for (int i = 0; i < ITERS; ++i, ++b) {
        // ---- commit staged tile (regs -> LDS), linear b128 writes ----
#pragma unroll
        for (int k = 0; k < 12; ++k) h4[tid + k * 512] = stg[k];
        if (tid < 256) h4[tid + 12 * 512] = stg[12];
        if (tid < 128) s_tw[tid] = twstg;
        __syncthreads();

        // ---- issue next tile's loads; in flight across all compute below ----
        if (i + 1 < ITERS) {
            const f32x4* gh2 = (const f32x4*)hist + (size_t)(b + 1) * NG;
#pragma unroll
            for (int k = 0; k < 12; ++k) stg[k] = gh2[gidx[k]];
            if (tid < 256) stg[12] = gh2[gidx[12]];
            if (tid < 128) twstg = TW[(size_t)(b + 1) * D_EMB + tid];
        }

        // ---- MFMA: h_pre = hist_tile @ W, then logits = relu(h_pre+tw).q ----
        for (int mt = p; mt < 13; mt += 4) {
            f32x4 acc[4];
#pragma unroll
            for (int j = 0; j < 4; ++j) acc[j] = vzero;
            const int t = mt * 16 + l15;  // A row
            const int sw = t & 7;
            const int trow = t * 32;
#pragma unroll
            for (int ks = 0; ks < 4; ++ks) {
                int c0 = ks * 8 + lg * 2;  // k-cols (l>>4)*8 + ks*32, as 2 granules
                f32x4 alo = h4[trow + (c0 ^ sw)];
                f32x4 ahi = h4[trow + ((c0 + 1) ^ sw)];
                bf16x8 A;
                A[0] = f2bf(alo[0]); A[1] = f2bf(alo[1]);
                A[2] = f2bf(alo[2]); A[3] = f2bf(alo[3]);
                A[4] = f2bf(ahi[0]); A[5] = f2bf(ahi[1]);
                A[6] = f2bf(ahi[2]); A[7] = f2bf(ahi[3]);
#pragma unroll
                for (int j = 0; j < 4; ++j)
                    acc[j] = __builtin_amdgcn_mfma_f32_16x16x32_bf16(A, Bf[ks][j], acc[j], 0, 0, 0);
            }
            // C/D layout: row = lg*4 + r, col = j*16 + l15 (+ hf*64)
            float part[4] = {0.f, 0.f, 0.f, 0.f};
#pragma unroll
            for (int j = 0; j < 4; ++j) {
                float twv = s_tw[hf * 64 + j * 16 + l15];
#pragma unroll
                for (int r = 0; r < 4; ++r)
                    part[r] += fmaxf(acc[j][r] + twv, 0.f) * qv[j];
            }
            // reduce over the 16 columns held across the 16-lane group
#pragma unroll
            for (int off = 1; off <= 8; off <<= 1)
#pragma unroll
                for (int r = 0; r < 4; ++r)
                    part[r] += __shfl_xor(part[r], off, 64);
            if (l15 == 0) {
                int row = mt * 16 + lg * 4;
                f32x4 v;
#pragma unroll
                for (int r = 0; r < 4; ++r)
                    v[r] = (row + r < T_HIST) ? part[r] : -1e30f;
                *(f32x4*)&s_logits[hf][row] = v;
            }
        }
        __syncthreads();

        // ---- softmax over T (unnormalized; divide at the end) ----
        float lv = (tid < T_PAD) ? (s_logits[0][tid] + s_logits[1][tid]) : -1e30f;
        float m = lv;
#pragma unroll
        for (int off = 32; off >= 1; off >>= 1)
            m = fmaxf(m, __shfl_xor(m, off, 64));
        if (l == 0) s_red[w] = m;
        __syncthreads();
        float M = s_red[0];
#pragma unroll
        for (int k = 1; k < 8; ++k) M = fmaxf(M, s_red[k]);
        float e = (tid < T_PAD) ? __expf(lv - M) : 0.f;
        if (tid < T_PAD) s_scores[tid] = e;
        float sm = e;
#pragma unroll
        for (int off = 32; off >= 1; off >>= 1)
            sm += __shfl_xor(sm, off, 64);
        if (l == 0) s_red[8 + w] = sm;
        __syncthreads();
        float S = s_red[8];
#pragma unroll
        for (int k = 9; k < 16; ++k) S += s_red[k];

        // ---- pass 2: out_d = sum_t e_t * hist[t][d] / S ----
        {
            const int c = tid & 31;   // logical granule column (d = 4c..4c+3)
            const int ch = tid >> 5;  // 16 chunks x 13 rows
            f32x4 acc2 = vzero;
#pragma unroll
            for (int tt = 0; tt < 13; ++tt) {
                int t = ch * 13 + tt;
                float sc = s_scores[t];  // pad rows have score 0
                f32x4 hv = h4[t * 32 + (c ^ (t & 7))];
#pragma unroll
                for (int r2 = 0; r2 < 4; ++r2) acc2[r2] = fmaf(sc, hv[r2], acc2[r2]);
            }
            *(f32x4*)&s_p2[ch][c * 4] = acc2;
        }
        __syncthreads();
        if (tid < 128) {
            float o = 0.f;
#pragma unroll
            for (int k = 0; k < 16; ++k) o += s_p2[k][tid];
            out[(size_t)b * D_EMB + tid] = o / S;
        }
        // no trailing barrier needed: all h4/s_scores reads precede the p2 barrier
    }
}

extern "C" void kernel_launch(void* const* d_in, const int* in_sizes, int n_in,
                              void* d_out, int out_size, void* d_ws, size_t ws_size,
                              hipStream_t stream) {
    const float* target = (const float*)d_in[0];
    const float* hist   = (const float*)d_in[1];
    const float* Wk     = (const float*)d_in[2];
    const float* Wb     = (const float*)d_in[3];
    const float* qk     = (const float*)d_in[4];
    // d_in[5] (q_bias) is softmax-invariant -> dropped
    float* out = (float*)d_out;

    short* wfrag = (short*)d_ws;                       // 32 KB
    float* TW    = (float*)((char*)d_ws + 32768);      // 8 MB

    pack_w_kernel<<<dim3(8), dim3(256), 0, stream>>>(Wk, wfrag);
    tw_kernel<<<dim3(2048), dim3(128), 0, stream>>>(target, Wk, Wb, TW);
    attn_main<<<dim3(NBLK), dim3(512), 0, stream>>>(hist, TW, qk, wfrag, out);
}

// Round 5
// 456.038 us; speedup vs baseline: 1.0501x; 1.0501x over previous
//
#include <hip/hip_runtime.h>
#include <hip/hip_bf16.h>

#define D_EMB 128
#define T_HIST 200
#define T_PAD 208
#define NG 6400      // float4 granules per batch row: 200*128/4
#define NG_PAD 6656  // 208*32
#define ITERS 64
#define NBLK 256

typedef float f32x4 __attribute__((ext_vector_type(4)));
typedef short bf16x8 __attribute__((ext_vector_type(8)));

// manual RNE f32->bf16
__device__ __forceinline__ short f2bf(float f) {
    unsigned u = __builtin_bit_cast(unsigned, f);
    u += 0x7fffu + ((u >> 16) & 1u);
    return (short)(u >> 16);
}

// sum x over the 16-lane group (l&15) using DPP only (no LDS pipe).
// EMPIRICALLY VERIFIED equivalent to the shfl_xor reduce (rounds 2 vs 3
// produced bit-identical outputs with DPP vs shfl).
__device__ __forceinline__ float dpp_reduce16(float x) {
    int v = __builtin_bit_cast(int, x);
    x += __builtin_bit_cast(float, __builtin_amdgcn_update_dpp(0, v, 0xB1, 0xF, 0xF, true));  // quad xor1
    v = __builtin_bit_cast(int, x);
    x += __builtin_bit_cast(float, __builtin_amdgcn_update_dpp(0, v, 0x4E, 0xF, 0xF, true));  // quad xor2
    v = __builtin_bit_cast(int, x);
    x += __builtin_bit_cast(float, __builtin_amdgcn_update_dpp(0, v, 0x141, 0xF, 0xF, true)); // half-row mirror
    v = __builtin_bit_cast(int, x);
    x += __builtin_bit_cast(float, __builtin_amdgcn_update_dpp(0, v, 0x140, 0xF, 0xF, true)); // row mirror
    return x;
}

// Pack W [d][e] f32 into MFMA B-fragment order, bf16.
__global__ void pack_w_kernel(const float* __restrict__ W, short* __restrict__ wfrag) {
    int tid = blockIdx.x * blockDim.x + threadIdx.x;  // 0..2047
    int fragid = tid >> 6;
    int lane = tid & 63;
    int ks = fragid >> 3;
    int nt = fragid & 7;
    int n = nt * 16 + (lane & 15);
    int k0 = ks * 32 + (lane >> 4) * 8;
    bf16x8 r;
#pragma unroll
    for (int j = 0; j < 8; ++j) r[j] = f2bf(W[(k0 + j) * D_EMB + n]);
    ((bf16x8*)wfrag)[fragid * 64 + lane] = r;
}

// TW[b][e] = bias[e] + sum_d target[b][d] * W[d][e]   (full f32)
__global__ void tw_kernel(const float* __restrict__ target, const float* __restrict__ W,
                          const float* __restrict__ bias, float* __restrict__ TW) {
    int e = threadIdx.x;      // 0..127
    int b0 = blockIdx.x * 8;  // 8 rows per block amortizes W row reads
    float bv = bias[e];
    float acc[8];
#pragma unroll
    for (int i = 0; i < 8; ++i) acc[i] = bv;
    for (int d = 0; d < D_EMB; ++d) {
        float wv = W[d * D_EMB + e];
#pragma unroll
        for (int i = 0; i < 8; ++i)
            acc[i] = fmaf(target[(size_t)(b0 + i) * D_EMB + d], wv, acc[i]);
    }
#pragma unroll
    for (int i = 0; i < 8; ++i) TW[(size_t)(b0 + i) * D_EMB + e] = acc[i];
}

// Persistent fused kernel: round-1 structure verbatim (f32 LDS tile,
// granule XOR swizzle, p=w&3 / hf=w>>2, element-wise f2bf A-build).
// Deltas vs round 1: (1) DPP reduce instead of shfl_xor (verified
// equivalent), (2) twv hoisted out of the mt loop.
__launch_bounds__(512, 2)
__global__ void attn_main(const float* __restrict__ hist,
                          const float* __restrict__ TW,
                          const float* __restrict__ q,
                          const short* __restrict__ wfrag,
                          float* __restrict__ out) {
    __shared__ f32x4 h4[NG_PAD];             // 106496 B
    __shared__ float s_tw[D_EMB];            // 512 B
    __shared__ float s_logits[2][T_PAD];     // 1664 B
    __shared__ float s_scores[T_PAD];        // 832 B
    __shared__ float s_red[16];              // 64 B
    __shared__ float s_p2[16][D_EMB];        // 8192 B

    const int tid = threadIdx.x;
    const int l = tid & 63;
    const int w = tid >> 6;
    const int p = w & 3;    // m-tiles {p, p+4, p+8, p+12<13}
    const int hf = w >> 2;  // half: owns n-tiles hf*4 .. hf*4+3
    const int l15 = l & 15;
    const int lg = l >> 4;
    const f32x4 vzero = {0.f, 0.f, 0.f, 0.f};

    // resident B fragments: 4 ks x 4 local-nt = 64 VGPR, loaded once (L2-hot)
    bf16x8 Bf[4][4];
#pragma unroll
    for (int ks = 0; ks < 4; ++ks)
#pragma unroll
        for (int j = 0; j < 4; ++j)
            Bf[ks][j] = ((const bf16x8*)wfrag)[(ks * 8 + hf * 4 + j) * 64 + l];

    float qv[4];
#pragma unroll
    for (int j = 0; j < 4; ++j) qv[j] = q[hf * 64 + j * 16 + l15];

    // zero the 8 pad rows (t=200..207) once; never overwritten
    if (tid < 256) h4[NG + tid] = vzero;

    // per-thread global gather indices (constant across iterations):
    // physical granule s = tid + k*512 holds logical (t = s>>5, c = (s&31)^(t&7))
    int gidx[13];
#pragma unroll
    for (int k = 0; k < 13; ++k) {
        int s = tid + k * 512;
        int t = s >> 5;
        gidx[k] = t * 32 + ((s & 31) ^ (t & 7));
    }

    int b = blockIdx.x * ITERS;
    const f32x4* gh = (const f32x4*)hist + (size_t)b * NG;
    f32x4 stg[13];
#pragma unroll
    for (int k = 0; k < 12; ++k) stg[k] = gh[gidx[k]];
    if (tid < 256) stg[12] = gh[gidx[12]];
    float twstg = (tid < 128) ? TW[(size_t)b * D_EMB + tid] : 0.f;

    for (int i = 0; i < ITERS; ++i, ++b) {
        // ---- commit staged tile (regs -> LDS), linear b128 writes ----
#pragma unroll
        for (int k = 0; k < 12; ++k) h4[tid + k * 512] = stg[k];
        if (tid < 256) h4[tid + 12 * 512] = stg[12];
        if (tid < 128) s_tw[tid] = twstg;
        __syncthreads();

        // ---- issue next tile's loads; in flight across all compute below ----
        if (i + 1 < ITERS) {
            const f32x4* gh2 = (const f32x4*)hist + (size_t)(b + 1) * NG;
#pragma unroll
            for (int k = 0; k < 12; ++k) stg[k] = gh2[gidx[k]];
            if (tid < 256) stg[12] = gh2[gidx[12]];
            if (tid < 128) twstg = TW[(size_t)(b + 1) * D_EMB + tid];
        }

        // per-tile hoisted tw values for this wave's columns
        float twv[4];
#pragma unroll
        for (int j = 0; j < 4; ++j) twv[j] = s_tw[hf * 64 + j * 16 + l15];

        // ---- MFMA: h_pre = hist_tile @ W, then logits = relu(h_pre+tw).q ----
        for (int mt = p; mt < 13; mt += 4) {
            f32x4 acc[4];
#pragma unroll
            for (int j = 0; j < 4; ++j) acc[j] = vzero;
            const int t = mt * 16 + l15;  // A row
            const int sw = t & 7;
            const int trow = t * 32;
#pragma unroll
            for (int ks = 0; ks < 4; ++ks) {
                int c0 = ks * 8 + lg * 2;  // k-cols (l>>4)*8 + ks*32, as 2 granules
                f32x4 alo = h4[trow + (c0 ^ sw)];
                f32x4 ahi = h4[trow + ((c0 + 1) ^ sw)];
                bf16x8 A;
                A[0] = f2bf(alo[0]); A[1] = f2bf(alo[1]);
                A[2] = f2bf(alo[2]); A[3] = f2bf(alo[3]);
                A[4] = f2bf(ahi[0]); A[5] = f2bf(ahi[1]);
                A[6] = f2bf(ahi[2]); A[7] = f2bf(ahi[3]);
#pragma unroll
                for (int j = 0; j < 4; ++j)
                    acc[j] = __builtin_amdgcn_mfma_f32_16x16x32_bf16(A, Bf[ks][j], acc[j], 0, 0, 0);
            }
            // C/D layout: row = lg*4 + r, col = j*16 + l15 (+ hf*64)
            float part[4] = {0.f, 0.f, 0.f, 0.f};
#pragma unroll
            for (int j = 0; j < 4; ++j) {
#pragma unroll
                for (int r = 0; r < 4; ++r)
                    part[r] += fmaxf(acc[j][r] + twv[j], 0.f) * qv[j];
            }
            // reduce over the 16 columns held across the 16-lane group (DPP)
#pragma unroll
            for (int r = 0; r < 4; ++r) part[r] = dpp_reduce16(part[r]);
            if (l15 == 0) {
                int row = mt * 16 + lg * 4;
                f32x4 v;
#pragma unroll
                for (int r = 0; r < 4; ++r)
                    v[r] = (row + r < T_HIST) ? part[r] : -1e30f;
                *(f32x4*)&s_logits[hf][row] = v;
            }
        }
        __syncthreads();

        // ---- softmax over T (unnormalized; divide at the end) ----
        float lv = (tid < T_PAD) ? (s_logits[0][tid] + s_logits[1][tid]) : -1e30f;
        float m = lv;
#pragma unroll
        for (int off = 32; off >= 1; off >>= 1)
            m = fmaxf(m, __shfl_xor(m, off, 64));
        if (l == 0) s_red[w] = m;
        __syncthreads();
        float M = s_red[0];
#pragma unroll
        for (int k = 1; k < 8; ++k) M = fmaxf(M, s_red[k]);
        float e = (tid < T_PAD) ? __expf(lv - M) : 0.f;
        if (tid < T_PAD) s_scores[tid] = e;
        float sm = e;
#pragma unroll
        for (int off = 32; off >= 1; off >>= 1)
            sm += __shfl_xor(sm, off, 64);
        if (l == 0) s_red[8 + w] = sm;
        __syncthreads();
        float S = s_red[8];
#pragma unroll
        for (int k = 9; k < 16; ++k) S += s_red[k];

        // ---- pass 2: out_d = sum_t e_t * hist[t][d] / S ----
        {
            const int c = tid & 31;   // logical granule column (d = 4c..4c+3)
            const int ch = tid >> 5;  // 16 chunks x 13 rows
            f32x4 acc2 = vzero;
#pragma unroll
            for (int tt = 0; tt < 13; ++tt) {
                int t = ch * 13 + tt;
                float sc = s_scores[t];  // pad rows have score 0
                f32x4 hv = h4[t * 32 + (c ^ (t & 7))];
#pragma unroll
                for (int r2 = 0; r2 < 4; ++r2) acc2[r2] = fmaf(sc, hv[r2], acc2[r2]);
            }
            *(f32x4*)&s_p2[ch][c * 4] = acc2;
        }
        __syncthreads();
        if (tid < 128) {
            float o = 0.f;
#pragma unroll
            for (int k = 0; k < 16; ++k) o += s_p2[k][tid];
            out[(size_t)b * D_EMB + tid] = o / S;
        }
        // no trailing barrier needed: all h4/s_scores reads precede the p2 barrier
    }
}

extern "C" void kernel_launch(void* const* d_in, const int* in_sizes, int n_in,
                              void* d_out, int out_size, void* d_ws, size_t ws_size,
                              hipStream_t stream) {
    const float* target = (const float*)d_in[0];
    const float* hist   = (const float*)d_in[1];
    const float* Wk     = (const float*)d_in[2];
    const float* Wb     = (const float*)d_in[3];
    const float* qk     = (const float*)d_in[4];
    // d_in[5] (q_bias) is softmax-invariant -> dropped
    float* out = (float*)d_out;

    short* wfrag = (short*)d_ws;                       // 32 KB
    float* TW    = (float*)((char*)d_ws + 32768);      // 8 MB

    pack_w_kernel<<<dim3(8), dim3(256), 0, stream>>>(Wk, wfrag);
    tw_kernel<<<dim3(2048), dim3(128), 0, stream>>>(target, Wk, Wb, TW);
    attn_main<<<dim3(NBLK), dim3(512), 0, stream>>>(hist, TW, qk, wfrag, out);
}

// Round 6
// 366.458 us; speedup vs baseline: 1.3068x; 1.2444x over previous
//
#include <hip/hip_runtime.h>
#include <hip/hip_bf16.h>

#define D_EMB 128
#define T_HIST 200
#define T_PAD 208
#define NG 6400      // f32x4 granules per batch row
#define ITERS 64
#define NBLK 256

typedef float f32x4 __attribute__((ext_vector_type(4)));
typedef short bf16x8 __attribute__((ext_vector_type(8)));

__device__ __forceinline__ short f2bf(float f) {
    unsigned u = __builtin_bit_cast(unsigned, f);
    u += 0x7fffu + ((u >> 16) & 1u);
    return (short)(u >> 16);
}

// proven DPP 16-lane-group sum (rounds 2 vs 3 bit-identical vs shfl)
__device__ __forceinline__ float dpp_reduce16(float x) {
    int v = __builtin_bit_cast(int, x);
    x += __builtin_bit_cast(float, __builtin_amdgcn_update_dpp(0, v, 0xB1, 0xF, 0xF, true));
    v = __builtin_bit_cast(int, x);
    x += __builtin_bit_cast(float, __builtin_amdgcn_update_dpp(0, v, 0x4E, 0xF, 0xF, true));
    v = __builtin_bit_cast(int, x);
    x += __builtin_bit_cast(float, __builtin_amdgcn_update_dpp(0, v, 0x141, 0xF, 0xF, true));
    v = __builtin_bit_cast(int, x);
    x += __builtin_bit_cast(float, __builtin_amdgcn_update_dpp(0, v, 0x140, 0xF, 0xF, true));
    return x;
}

// f32x4 granule -> 4 packed RNE bf16 (8B), via HW packed convert (T12 recipe)
__device__ __forceinline__ uint2 cvt_granule(f32x4 v) {
    uint2 r;
    asm("v_cvt_pk_bf16_f32 %0, %1, %2" : "=v"(r.x) : "v"(v[0]), "v"(v[1]));
    asm("v_cvt_pk_bf16_f32 %0, %1, %2" : "=v"(r.y) : "v"(v[2]), "v"(v[3]));
    return r;
}

__global__ void pack_w_kernel(const float* __restrict__ W, short* __restrict__ wfrag) {
    int tid = blockIdx.x * blockDim.x + threadIdx.x;
    int fragid = tid >> 6;
    int lane = tid & 63;
    int ks = fragid >> 3;
    int nt = fragid & 7;
    int n = nt * 16 + (lane & 15);
    int k0 = ks * 32 + (lane >> 4) * 8;
    bf16x8 r;
#pragma unroll
    for (int j = 0; j < 8; ++j) r[j] = f2bf(W[(k0 + j) * D_EMB + n]);
    ((bf16x8*)wfrag)[fragid * 64 + lane] = r;
}

__global__ void tw_kernel(const float* __restrict__ target, const float* __restrict__ W,
                          const float* __restrict__ bias, float* __restrict__ TW) {
    int e = threadIdx.x;
    int b0 = blockIdx.x * 8;
    float bv = bias[e];
    float acc[8];
#pragma unroll
    for (int i = 0; i < 8; ++i) acc[i] = bv;
    for (int d = 0; d < D_EMB; ++d) {
        float wv = W[d * D_EMB + e];
#pragma unroll
        for (int i = 0; i < 8; ++i)
            acc[i] = fmaf(target[(size_t)(b0 + i) * D_EMB + d], wv, acc[i]);
    }
#pragma unroll
    for (int i = 0; i < 8; ++i) TW[(size_t)(b0 + i) * D_EMB + e] = acc[i];
}

// Layout: thread tid = r*32 + cc (r = tid>>5, cc = tid&31) owns, for k=0..12,
// logical granule (t = r + 16k, c_log = ((cc>>1) ^ (r&7))<<1 | (cc&1)).
// c_log is THREAD-CONSTANT -> staged f32 regs give this thread's exact pass-2
// contribution for columns 4*c_log..4*c_log+3. LDS half-granule q = tid + k*512
// holds bf16 of that granule; MFMA A (logical pair P of row t) reads physical
// pair  (t&15)*16 + (P ^ (t&7)) + (t>>4)*256  as ONE ds_read_b128 via
// pointer-cast load (proven Bf pattern; no value-bitcast).
__launch_bounds__(512, 2)
__global__ void attn_main(const float* __restrict__ hist,
                          const float* __restrict__ TW,
                          const float* __restrict__ q,
                          const short* __restrict__ wfrag,
                          float* __restrict__ out) {
    __shared__ __align__(16) uint2 h2[2][T_PAD * 32];  // 2 x 53248 B bf16 tiles
    __shared__ float s_tw[2][D_EMB];
    __shared__ float s_logits[2][T_PAD];
    __shared__ float s_scores[T_PAD];
    __shared__ float s_red[16];
    __shared__ float s_p2[16][D_EMB];

    const int tid = threadIdx.x;
    const int l = tid & 63;
    const int w = tid >> 6;
    const int p = w & 3;
    const int hf = w >> 2;
    const int l15 = l & 15;
    const int lg = l >> 4;
    const int r = tid >> 5;
    const int cc = tid & 31;
    const int c_log = (((cc >> 1) ^ (r & 7)) << 1) | (cc & 1);
    const int base_g = r * 32 + c_log;  // + k*512 per k
    const f32x4 vzero = {0.f, 0.f, 0.f, 0.f};

    bf16x8 Bf[4][4];
#pragma unroll
    for (int ks = 0; ks < 4; ++ks)
#pragma unroll
        for (int j = 0; j < 4; ++j)
            Bf[ks][j] = ((const bf16x8*)wfrag)[(ks * 8 + hf * 4 + j) * 64 + l];

    float qv[4];
#pragma unroll
    for (int j = 0; j < 4; ++j) qv[j] = q[hf * 64 + j * 16 + l15];

    // zero pad rows (t=200..207 live at q in [6400,6656)) in both buffers
    if (tid >= 256) {
        h2[0][6144 + tid] = uint2{0u, 0u};
        h2[1][6144 + tid] = uint2{0u, 0u};
    }

    const int base = blockIdx.x * ITERS;
    const f32x4* ghist = (const f32x4*)hist;

    f32x4 stgA[13], stgB[13];
    float twA = 0.f, twB = 0.f;

    {   // prologue: load tile 0 + issue tile 1
        const f32x4* g0 = ghist + (size_t)base * NG + base_g;
#pragma unroll
        for (int k = 0; k < 12; ++k) stgA[k] = g0[k * 512];
        if (tid < 256) stgA[12] = g0[12 * 512];
        if (tid < 128) twA = TW[(size_t)base * D_EMB + tid];
        const f32x4* g1 = ghist + (size_t)(base + 1) * NG + base_g;
#pragma unroll
        for (int k = 0; k < 12; ++k) stgB[k] = g1[k * 512];
        if (tid < 256) stgB[12] = g1[12 * 512];
        if (tid < 128) twB = TW[(size_t)(base + 1) * D_EMB + tid];
    }
    {   // commit tile 0 -> h2[0]
        uint2* d = h2[0];
#pragma unroll
        for (int k = 0; k < 12; ++k) d[tid + k * 512] = cvt_granule(stgA[k]);
        if (tid < 256) d[tid + 12 * 512] = cvt_granule(stgA[12]);
        if (tid < 128) s_tw[0][tid] = twA;
    }
    __syncthreads();

#define BODY(PAR, STG_CUR, STG_OTH, TW_CUR, TW_OTH, II)                           \
    {                                                                             \
        const int bb = base + (II);                                               \
        float twv[4];                                                             \
        _Pragma("unroll") for (int j = 0; j < 4; ++j)                             \
            twv[j] = s_tw[PAR][hf * 64 + j * 16 + l15];                           \
        const bf16x8* hp = (const bf16x8*)h2[PAR];                                \
        for (int mt = p; mt < 13; mt += 4) {                                      \
            f32x4 acc[4];                                                         \
            _Pragma("unroll") for (int j = 0; j < 4; ++j) acc[j] = vzero;         \
            _Pragma("unroll") for (int ks = 0; ks < 4; ++ks) {                    \
                bf16x8 A = hp[l15 * 16 + ((ks * 4 + lg) ^ (l15 & 7)) + mt * 256]; \
                _Pragma("unroll") for (int j = 0; j < 4; ++j)                     \
                    acc[j] = __builtin_amdgcn_mfma_f32_16x16x32_bf16(             \
                        A, Bf[ks][j], acc[j], 0, 0, 0);                           \
            }                                                                     \
            float part[4] = {0.f, 0.f, 0.f, 0.f};                                 \
            _Pragma("unroll") for (int j = 0; j < 4; ++j) {                       \
                _Pragma("unroll") for (int rr = 0; rr < 4; ++rr)                  \
                    part[rr] += fmaxf(acc[j][rr] + twv[j], 0.f) * qv[j];          \
            }                                                                     \
            _Pragma("unroll") for (int rr = 0; rr < 4; ++rr)                      \
                part[rr] = dpp_reduce16(part[rr]);                                \
            if (l15 == 0) {                                                       \
                int row = mt * 16 + lg * 4;                                       \
                f32x4 v;                                                          \
                _Pragma("unroll") for (int rr = 0; rr < 4; ++rr)                  \
                    v[rr] = (row + rr < T_HIST) ? part[rr] : -1e30f;              \
                *(f32x4*)&s_logits[hf][row] = v;                                  \
            }                                                                     \
        }                                                                         \
        /* commit tile II+1 into the other LDS buffer (regs stay intact) */       \
        if ((II) + 1 < ITERS) {                                                   \
            uint2* d = h2[1 - (PAR)];                                             \
            _Pragma("unroll") for (int k = 0; k < 12; ++k)                        \
                d[tid + k * 512] = cvt_granule(STG_OTH[k]);                       \
            if (tid < 256) d[tid + 12 * 512] = cvt_granule(STG_OTH[12]);          \
            if (tid < 128) s_tw[1 - (PAR)][tid] = TW_OTH;                         \
        }                                                                         \
        __syncthreads();                                                          \
        float lv = (tid < T_PAD) ? (s_logits[0][tid] + s_logits[1][tid]) : -1e30f;\
        float m = lv;                                                             \
        _Pragma("unroll") for (int off = 32; off >= 1; off >>= 1)                 \
            m = fmaxf(m, __shfl_xor(m, off, 64));                                 \
        if (l == 0) s_red[w] = m;                                                 \
        __syncthreads();                                                          \
        float M = s_red[0];                                                       \
        _Pragma("unroll") for (int k = 1; k < 8; ++k) M = fmaxf(M, s_red[k]);     \
        float e = (tid < T_PAD) ? __expf(lv - M) : 0.f;                           \
        if (tid < T_PAD) s_scores[tid] = e;                                       \
        float sm = e;                                                             \
        _Pragma("unroll") for (int off = 32; off >= 1; off >>= 1)                 \
            sm += __shfl_xor(sm, off, 64);                                        \
        if (l == 0) s_red[8 + w] = sm;                                            \
        __syncthreads();                                                          \
        float S = s_red[8];                                                       \
        _Pragma("unroll") for (int k = 9; k < 16; ++k) S += s_red[k];             \
        /* pass 2 from exact f32 registers */                                     \
        f32x4 acc2 = vzero;                                                       \
        _Pragma("unroll") for (int k = 0; k < 12; ++k) {                          \
            float sc = s_scores[r + 16 * k];                                      \
            _Pragma("unroll") for (int rr = 0; rr < 4; ++rr)                      \
                acc2[rr] = fmaf(sc, STG_CUR[k][rr], acc2[rr]);                    \
        }                                                                         \
        if (tid < 256) {                                                          \
            float sc = s_scores[r + 192];                                         \
            _Pragma("unroll") for (int rr = 0; rr < 4; ++rr)                      \
                acc2[rr] = fmaf(sc, STG_CUR[12][rr], acc2[rr]);                   \
        }                                                                         \
        *(f32x4*)&s_p2[r][c_log * 4] = acc2;                                      \
        __syncthreads();                                                          \
        if (tid < 128) {                                                          \
            float o = 0.f;                                                        \
            _Pragma("unroll") for (int k = 0; k < 16; ++k) o += s_p2[k][tid];     \
            out[(size_t)bb * D_EMB + tid] = o / S;                                \
        }                                                                         \
        /* prefetch tile II+2 into STG_CUR (last use of STG_CUR was pass 2) */    \
        if ((II) + 2 < ITERS) {                                                   \
            const f32x4* gn = ghist + (size_t)(bb + 2) * NG + base_g;             \
            _Pragma("unroll") for (int k = 0; k < 12; ++k) STG_CUR[k] = gn[k*512];\
            if (tid < 256) STG_CUR[12] = gn[12 * 512];                            \
            if (tid < 128) TW_CUR = TW[(size_t)(bb + 2) * D_EMB + tid];           \
        }                                                                         \
    }

    for (int ii = 0; ii < ITERS; ii += 2) {
        BODY(0, stgA, stgB, twA, twB, ii)
        BODY(1, stgB, stgA, twB, twA, ii + 1)
    }
#undef BODY
}

extern "C" void kernel_launch(void* const* d_in, const int* in_sizes, int n_in,
                              void* d_out, int out_size, void* d_ws, size_t ws_size,
                              hipStream_t stream) {
    const float* target = (const float*)d_in[0];
    const float* hist   = (const float*)d_in[1];
    const float* Wk     = (const float*)d_in[2];
    const float* Wb     = (const float*)d_in[3];
    const float* qk     = (const float*)d_in[4];
    float* out = (float*)d_out;

    short* wfrag = (short*)d_ws;                   // 32 KB
    float* TW    = (float*)((char*)d_ws + 32768);  // 8 MB

    pack_w_kernel<<<dim3(8), dim3(256), 0, stream>>>(Wk, wfrag);
    tw_kernel<<<dim3(2048), dim3(128), 0, stream>>>(target, Wk, Wb, TW);
    attn_main<<<dim3(NBLK), dim3(512), 0, stream>>>(hist, TW, qk, wfrag, out);
}